// Round 9
// baseline (370.426 us; speedup 1.0000x reference)
//
#include <hip/hip_runtime.h>
#include <hip/hip_fp16.h>

typedef __half f16;
typedef _Float16 h8 __attribute__((ext_vector_type(8)));
typedef _Float16 h4 __attribute__((ext_vector_type(4)));
typedef _Float16 h2 __attribute__((ext_vector_type(2)));
typedef float f32x4 __attribute__((ext_vector_type(4)));

#define NN 255          // real nodes
#define BB 512          // batch
#define TSS 264         // T LDS row stride in f16

static __device__ __forceinline__ f16 f2h(float x) { return __float2half(x); }

union H8u { h8 v; h2 p[4]; };

// ---------------- setup kernels (tiny, one-time) ----------------

__global__ void zero_k(float* p, int n) {
    int i = blockIdx.x * 256 + threadIdx.x;
    if (i < n) p[i] = 0.f;
}

__global__ void scatter_k(const int* __restrict__ idx, const float* __restrict__ vals,
                          float* __restrict__ dad, int nnz) {
    int t = blockIdx.x * 256 + threadIdx.x;
    if (t < nnz) atomicAdd(&dad[idx[2 * t] * 256 + idx[2 * t + 1]], vals[t]);
}

// rsm[i] = sum_k dadsm[i][k] (i<255), rsm[255]=0
__global__ void rowsum_k(const float* __restrict__ dad, float* __restrict__ r) {
    int i = blockIdx.x * 64 + threadIdx.x;
    if (i < 256) {
        float s = 0.f;
        if (i < NN) for (int k = 0; k < NN; k++) s += dad[i * 256 + k];
        r[i] = s;
    }
}

// dadp[k/8][node][8] = DAD[node][k] as f16; node 255 row zero, col 255 zero by construction
__global__ void convert_dad(const float* __restrict__ dadf, f16* __restrict__ dadp) {
    int i = blockIdx.x * 256 + threadIdx.x;   // over 2*65536
    int which = i >> 16, rc = i & 65535;
    int node = rc >> 8, k = rc & 255;
    float v = (node < NN) ? dadf[(size_t)which * NN * 256 + rc] : 0.f;
    dadp[(size_t)which * 65536 + (((k >> 3) * 256 + node) << 3) + (k & 7)] = f2h(v);
}

// Wtp[tile][k/8][feat(64)][8] = W[k][feat], zero-padded (feats >= N, k >= K)
__global__ void convert_wt(const float* __restrict__ W, f16* __restrict__ Wtp,
                           int K, int N, int KPB) {
    int f = blockIdx.x;                 // padded feat index (ntiles*64 blocks)
    int tile = f >> 6, fl = f & 63;
    int Kpad = KPB * 8;
    for (int k = threadIdx.x; k < Kpad; k += 256) {
        float v = (f < N && k < K) ? W[(size_t)k * N + f] : 0.f;
        Wtp[((((size_t)tile * KPB + (k >> 3)) * 64 + fl) << 3) + (k & 7)] = f2h(v);
    }
}

// T0f[b][node][2] = (DADsm @ H)[node] f32; node 255 -> 0. One wave per (b,node).
__global__ __launch_bounds__(256) void dad2_in(const float* __restrict__ dad,
                                               const float* __restrict__ H,
                                               float* __restrict__ T0f) {
    int gw = (blockIdx.x * 256 + threadIdx.x) >> 6;
    int lane = threadIdx.x & 63;
    if (gw >= BB * 256) return;
    int b = gw >> 8, i = gw & 255;
    if (i == NN) {
        if (lane == 0) { T0f[(size_t)gw * 2] = 0.f; T0f[(size_t)gw * 2 + 1] = 0.f; }
        return;
    }
    const float* dr = dad + (size_t)i * 256;
    const float* yb = H + (size_t)b * NN * 2;
    float a0 = 0.f, a1 = 0.f;
    for (int k = lane; k < NN; k += 64) {
        float d = dr[k];
        a0 += d * yb[2 * k];
        a1 += d * yb[2 * k + 1];
    }
#pragma unroll
    for (int off = 32; off > 0; off >>= 1) {
        a0 += __shfl_down(a0, off);
        a1 += __shfl_down(a1, off);
    }
    if (lane == 0) {
        T0f[(size_t)gw * 2 + 0] = a0;
        T0f[(size_t)gw * 2 + 1] = a1;
    }
}

// ============ fused layer: Xn = relu( DAD @ (X@W + bias) ) ============
// 1D grid, XCD-aware id mapping + LIFO (rev) batch order for L2 reuse across layers.
// Stage 1: T = (X[b] @ W_tile)^T + bias.
//   R2 variant (L1): X fragments are computed in-register as relu(rank-2 expansion of L0):
//   af[node][k] = relu(a0*W0[0][k] + a1*W0[1][k] + r*b0[k]) with W0/b0 staged in LDS and
//   (a0,a1,r) per-node scalars from T0f = DADsm@H. No X reads at all.
//   Non-R2: af ring-2 prefetched from global; bf (Wtp, L2-hot) loaded in-loop.
// Stage 2: out = DAD @ T; b2 (dadp) ring-2 prefetch, a2 from LDS T.
// CT = number of 16-feat column tiles (4 normal, 1 for the 2-feat final layer).
template <int KPB, int CT, bool R2, bool OUTF32>
__global__ __launch_bounds__(256, 4) void fused_layer(
        const f16* __restrict__ X,      // [512][KPB][256][8] zero-padded (unused if R2)
        const f16* __restrict__ Wtp,    // [ntiles][KPB][64][8] zero-padded
        const float* __restrict__ bias, // [Nout] f32
        const f16* __restrict__ dadp,   // [32][256][8]
        void* __restrict__ Xn_,         // f16 [512][SN/8][256][8]  (or f32 [512][255][2] if OUTF32)
        int Nout, int SN, int ntiles, int rev,
        const float* __restrict__ T0p,  // R2: [512][256][2] f32
        const float* __restrict__ rsmp, // R2: [256] f32 (row-sums, [255]=0)
        const float* __restrict__ W0f,  // R2: [2][400] f32
        const float* __restrict__ b0f) {// R2: [400] f32
    __shared__ _Float16 T[64 * TSS];
    __shared__ _Float16 WL[R2 ? 1344 : 4];   // 3 x 448-half rows: W0 row0, row1, b0
    const int id = blockIdx.x;
    int s = id >> 3;
    int bq = s / ntiles;
    const int tile = s - bq * ntiles;
    if (rev) bq = 63 - bq;
    const int b = ((id & 7) << 6) + bq;
    const int n0 = tile * 64;
    const int tid = threadIdx.x;
    const int w = tid >> 6;
    const int ln = tid & 15;
    const int q = (tid >> 4) & 3;

    // ---- R2 prologue: stage W0/b0 into LDS (f16), load per-node rank-2 scalars ----
    h2 a0s[4], a1s[4], rvs[4];
    if constexpr (R2) {
        for (int i2 = tid; i2 < 448; i2 += 256) {
            _Float16 va = (_Float16)(i2 < 400 ? W0f[i2] : 0.f);
            _Float16 vb = (_Float16)(i2 < 400 ? W0f[400 + i2] : 0.f);
            _Float16 vc = (_Float16)(i2 < 400 ? b0f[i2] : 0.f);
            WL[i2] = va; WL[448 + i2] = vb; WL[896 + i2] = vc;
        }
#pragma unroll
        for (int t = 0; t < 4; t++) {
            int node = 64 * w + 16 * t + ln;
            const float* tp = T0p + ((size_t)b * 256 + node) * 2;
            _Float16 x0 = (_Float16)tp[0];
            _Float16 x1 = (_Float16)tp[1];
            _Float16 rv = (_Float16)rsmp[node];
            a0s[t] = (h2){x0, x0};
            a1s[t] = (h2){x1, x1};
            rvs[t] = (h2){rv, rv};
        }
        __syncthreads();
    }

    // ---- stage 1: wave w: nodes 64w..64w+63 (4 A-tiles) x CT*16 feats (B-tiles) ----
    f32x4 acc[4][CT];
#pragma unroll
    for (int t = 0; t < 4; t++)
#pragma unroll
        for (int c = 0; c < CT; c++) acc[t][c] = (f32x4){0.f, 0.f, 0.f, 0.f};

    const f16* xb = R2 ? (const f16*)nullptr : X + (size_t)b * KPB * 2048;
    const f16* wp = Wtp + (size_t)tile * KPB * 512;

    h8 afr[2][4];
    if constexpr (!R2) {
#pragma unroll
        for (int t = 0; t < 4; t++)
            afr[0][t] = *(const h8*)(xb + ((q * 256 + 64 * w + 16 * t + ln) << 3));
    }

#pragma unroll
    for (int kb = 0; kb < KPB; kb += 4) {
        const int cur = (kb >> 2) & 1, nxt = cur ^ 1;
        h8 bf[CT];
#pragma unroll
        for (int c = 0; c < CT; c++)
            bf[c] = *(const h8*)(wp + (((kb + q) * 64 + 16 * c + ln) << 3));
        h8 afc[4];
        if constexpr (R2) {
            H8u wa, wb, bl;
            wa.v = *(const h8*)&WL[(kb + q) * 8];
            wb.v = *(const h8*)&WL[448 + (kb + q) * 8];
            bl.v = *(const h8*)&WL[896 + (kb + q) * 8];
            const h2 z2 = (h2){(_Float16)0.f, (_Float16)0.f};
#pragma unroll
            for (int t = 0; t < 4; t++) {
                H8u r;
#pragma unroll
                for (int j = 0; j < 4; j++)
                    r.p[j] = __builtin_elementwise_max(
                        a0s[t] * wa.p[j] + a1s[t] * wb.p[j] + rvs[t] * bl.p[j], z2);
                afc[t] = r.v;
            }
        } else {
            if (kb + 4 < KPB) {
#pragma unroll
                for (int t = 0; t < 4; t++)
                    afr[nxt][t] = *(const h8*)(xb + (((kb + 4 + q) * 256 + 64 * w + 16 * t + ln) << 3));
            }
#pragma unroll
            for (int t = 0; t < 4; t++) afc[t] = afr[cur][t];
        }
#pragma unroll
        for (int c = 0; c < CT; c++)
#pragma unroll
            for (int t = 0; t < 4; t++)
                acc[t][c] = __builtin_amdgcn_mfma_f32_16x16x32_f16(afc[t], bf[c], acc[t][c], 0, 0, 0);
    }

    // bias + pack to T[feat][node]; lane holds 4 consecutive nodes -> b64 writes
#pragma unroll
    for (int c = 0; c < CT; c++) {
        int fl = 16 * c + ln;
        int gf = n0 + fl;
        float bv = (gf < Nout) ? bias[gf] : 0.f;
#pragma unroll
        for (int t = 0; t < 4; t++) {
            h4 pk;
#pragma unroll
            for (int rg = 0; rg < 4; rg++) pk[rg] = (_Float16)(acc[t][c][rg] + bv);
            *(h4*)&T[fl * TSS + 64 * w + 16 * t + q * 4] = pk;
        }
    }
    __syncthreads();

    // ---- stage 2: wave w: CT*16 feats (A-op from T) x node_outs 64w..64w+63 (4 B-tiles) ----
    f32x4 acc2[CT][4];
#pragma unroll
    for (int f = 0; f < CT; f++)
#pragma unroll
        for (int t = 0; t < 4; t++) acc2[f][t] = (f32x4){0.f, 0.f, 0.f, 0.f};

    h8 b2[2][4];
#pragma unroll
    for (int t = 0; t < 4; t++)
        b2[0][t] = *(const h8*)(dadp + ((q * 256 + 64 * w + 16 * t + ln) << 3));

#pragma unroll
    for (int kb = 0; kb < 32; kb += 4) {
        const int cur = (kb >> 2) & 1, nxt = cur ^ 1;
        if (kb + 4 < 32) {
#pragma unroll
            for (int t = 0; t < 4; t++)
                b2[nxt][t] = *(const h8*)(dadp + (((kb + 4 + q) * 256 + 64 * w + 16 * t + ln) << 3));
        }
        h8 a2[CT];
#pragma unroll
        for (int f = 0; f < CT; f++)
            a2[f] = *(const h8*)&T[(16 * f + ln) * TSS + (kb + q) * 8];
#pragma unroll
        for (int t = 0; t < 4; t++)
#pragma unroll
            for (int f = 0; f < CT; f++)
                acc2[f][t] = __builtin_amdgcn_mfma_f32_16x16x32_f16(a2[f], b2[cur][t], acc2[f][t], 0, 0, 0);
    }

    if (!OUTF32) {
        // relu; store into next layer's k-panel layout (2x256B segments per store inst)
        f16* xn = (f16*)Xn_ + (size_t)b * (SN >> 3) * 2048;
#pragma unroll
        for (int f = 0; f < CT; f++) {
            int fb = n0 + 16 * f + q * 4;     // 4 consecutive feats
            if (fb >= SN) continue;
            int fb8 = fb >> 3, off = fb & 7;  // off in {0,4}
#pragma unroll
            for (int t = 0; t < 4; t++) {
                int node = 64 * w + 16 * t + ln;
                h4 pk;
#pragma unroll
                for (int rg = 0; rg < 4; rg++) pk[rg] = (_Float16)fmaxf(acc2[f][t][rg], 0.f);
                *(h4*)(xn + (((size_t)fb8 * 256 + node) << 3) + off) = pk;
            }
        }
    } else {
        // final layer: feats 0,1 live in f=0, q=0, rg=0..1; f32 compact store
        if (q == 0) {
            float* op = (float*)Xn_;
#pragma unroll
            for (int t = 0; t < 4; t++) {
                int node = 64 * w + 16 * t + ln;
                if (node < NN) {
                    float2 v;
                    v.x = fmaxf(acc2[0][t][0], 0.f);
                    v.y = fmaxf(acc2[0][t][1], 0.f);
                    *(float2*)(op + ((size_t)b * NN + node) * 2) = v;
                }
            }
        }
    }
}

// ---------------- launcher ----------------

extern "C" void kernel_launch(void* const* d_in, const int* in_sizes, int n_in,
                              void* d_out, int out_size, void* d_ws, size_t ws_size,
                              hipStream_t stream) {
    const float* H   = (const float*)d_in[0];
    const float* W[6]  = {(const float*)d_in[3], (const float*)d_in[5], (const float*)d_in[7],
                          (const float*)d_in[9], (const float*)d_in[11], (const float*)d_in[13]};
    const float* Bv[6] = {(const float*)d_in[4], (const float*)d_in[6], (const float*)d_in[8],
                          (const float*)d_in[10], (const float*)d_in[12], (const float*)d_in[14]};
    const int* smi = (const int*)d_in[15];
    const int* spi = (const int*)d_in[16];

    char* p = (char*)d_ws;
    f16* bufA = (f16*)p;            p += 109051904;   // [512][52][256][8]  (X2, X4)
    f16* bufB = (f16*)p;            p += 83886080;    // [512][40][256][8]  (X1, X3)
    float* dadsm = (float*)p;       p += 261120;      // [255][256] f32
    float* dadsp = (float*)p;       p += 261120;
    f16* dadpsm = (f16*)p;          p += 131072;      // [32][256][8] f16 k-panel
    f16* dadpsp = (f16*)p;          p += 131072;
    f16* Wt1 = (f16*)p;             p += 266240;      // [5][52][64][8]
    f16* Wt2 = (f16*)p;             p += 81920;       // [2][40][64][8]
    f16* Wt3 = (f16*)p;             p += 81920;       // [5][16][64][8]
    f16* Wt4 = (f16*)p;             p += 286720;      // [7][40][64][8]
    f16* Wt5 = (f16*)p;             p += 53248;       // [1][52][64][8]
    float* T0f = (float*)p;         p += 1048576;     // [512][256][2] f32
    float* rsm = (float*)p;         p += 1024;        // [256] f32

    // ---- build DAD + weight conversion + L0 rank-2 inputs ----
    zero_k<<<510, 256, 0, stream>>>(dadsm, 2 * NN * 256);
    scatter_k<<<10, 256, 0, stream>>>(smi, (const float*)d_in[1], dadsm, 2550);
    scatter_k<<<10, 256, 0, stream>>>(spi, (const float*)d_in[2], dadsp, 2550);
    rowsum_k<<<4, 64, 0, stream>>>(dadsm, rsm);
    convert_dad<<<512, 256, 0, stream>>>(dadsm, dadpsm);
    convert_wt<<<320, 256, 0, stream>>>(W[1], Wt1, 400, 300, 52);
    convert_wt<<<128, 256, 0, stream>>>(W[2], Wt2, 300, 100, 40);
    convert_wt<<<320, 256, 0, stream>>>(W[3], Wt3, 100, 300, 16);
    convert_wt<<<448, 256, 0, stream>>>(W[4], Wt4, 300, 400, 40);
    convert_wt<<<64, 256, 0, stream>>>(W[5], Wt5, 400, 2, 52);
    dad2_in<<<(BB * 256 * 64) / 256, 256, 0, stream>>>(dadsm, H, T0f);

    // ---- five fused layers (L0 folded into L1 as rank-2 A-fragment generation) ----
    // L0+L1: X1 = relu(DADsm @ (relu((DADsm H) W0 + r b0) W1 + b1))
    fused_layer<52, 4, true,  false><<<BB * 5, 256, 0, stream>>>(
        nullptr, Wt1, Bv[1], dadpsm, bufB, 300, 320, 5, 0, T0f, rsm, W[0], Bv[0]);
    // L2 enc2 (300->100)
    fused_layer<40, 4, false, false><<<BB * 2, 256, 0, stream>>>(
        bufB, Wt2, Bv[2], dadpsm, bufA, 100, 128, 2, 1, nullptr, nullptr, nullptr, nullptr);
    // L3 dec0 (100->300)
    fused_layer<16, 4, false, false><<<BB * 5, 256, 0, stream>>>(
        bufA, Wt3, Bv[3], dadpsp, bufB, 300, 320, 5, 0, nullptr, nullptr, nullptr, nullptr);
    // L4 dec1 (300->400)
    fused_layer<40, 4, false, false><<<BB * 7, 256, 0, stream>>>(
        bufB, Wt4, Bv[4], dadpsp, bufA, 400, 416, 7, 1, nullptr, nullptr, nullptr, nullptr);
    // L5 dec2 (400->2): narrow (CT=1), writes f32 d_out compact
    fused_layer<52, 1, false, true ><<<BB * 1, 256, 0, stream>>>(
        bufA, Wt5, Bv[5], dadpsp, d_out, 2, 2, 1, 0, nullptr, nullptr, nullptr, nullptr);
}